// Round 2
// baseline (3719.945 us; speedup 1.0000x reference)
//
#include <hip/hip_runtime.h>
#include <math.h>

#define NN 50000
#define NE 600000
#define NG 512

// ---------------- edge scatter: agg[dst][c] += x[src][c]; deg[dst] += 1 ----------------
template<bool ADD_DEG>
__global__ __launch_bounds__(256)
void scatter_k(const float* __restrict__ x, const int* __restrict__ ei,
               float* __restrict__ agg, float* __restrict__ deg) {
  int tid = blockIdx.x * 256 + threadIdx.x;
  int e = tid >> 5;
  if (e >= NE) return;
  int q = tid & 31;
  int src = ei[e];
  int dst = ei[NE + e];
  float4 p = *(const float4*)(x + (size_t)src * 128 + q * 4);
  float* ar = agg + (size_t)dst * 128 + q * 4;
  atomicAdd(ar + 0, p.x);
  atomicAdd(ar + 1, p.y);
  atomicAdd(ar + 2, p.z);
  atomicAdd(ar + 3, p.w);
  if (ADD_DEG && q == 0) atomicAdd(deg + dst, 1.0f);
}

// ---------------- fused SAGE layer, Cout=128: out = (agg/deg)@Wl + bl + x@Wr ----------------
// block = 256 (4 waves); wave owns 4 rows; lane owns output channels (lane, lane+64).
// Two passes (Wl then Wr) since 2 x 64KB f32 weights don't fit in 64KB LDS.
template<bool WRITE_PRE>
__global__ __launch_bounds__(256)
void sage128_k(const float* __restrict__ x, const float* __restrict__ agg,
               const float* __restrict__ deg,
               const float* __restrict__ Wl, const float* __restrict__ bl,
               const float* __restrict__ Wr,
               float* __restrict__ out_relu, float* __restrict__ out_pre) {
  __shared__ __align__(16) float sW[128 * 128];   // 64 KB, reused across the two passes
  int wave = threadIdx.x >> 6;
  int lane = threadIdx.x & 63;
  int r0 = blockIdx.x * 16 + wave * 4;   // 3125 blocks * 16 = 50000 exactly

  float acc[4][2];
#pragma unroll
  for (int i = 0; i < 4; i++) { acc[i][0] = 0.0f; acc[i][1] = 0.0f; }
  float inv[4];
#pragma unroll
  for (int i = 0; i < 4; i++) inv[i] = 1.0f / fmaxf(deg[r0 + i], 1.0f);

  for (int pass = 0; pass < 2; pass++) {
    const float* Wg = pass ? Wr : Wl;
    const float* src = pass ? x : agg;
    __syncthreads();   // all waves done reading previous pass's sW
    {
      const float4* g = (const float4*)Wg;
      float4* s = (float4*)sW;
      for (int i = threadIdx.x; i < 4096; i += 256) s[i] = g[i];
    }
    __syncthreads();

    for (int kb = 0; kb < 16; kb++) {
      int k0 = kb * 8;
      float w0[8], w1[8];
#pragma unroll
      for (int j = 0; j < 8; j++) {
        w0[j] = sW[(k0 + j) * 128 + lane];
        w1[j] = sW[(k0 + j) * 128 + 64 + lane];
      }
#pragma unroll
      for (int i = 0; i < 4; i++) {
        int r = r0 + i;
        float4 a0 = *(const float4*)(src + (size_t)r * 128 + k0);
        float4 a1 = *(const float4*)(src + (size_t)r * 128 + k0 + 4);
        float vin[8] = {a0.x, a0.y, a0.z, a0.w, a1.x, a1.y, a1.z, a1.w};
        float scale = pass ? 1.0f : inv[i];
#pragma unroll
        for (int j = 0; j < 8; j++) {
          float an = vin[j] * scale;
          acc[i][0] = fmaf(an, w0[j], acc[i][0]);
          acc[i][1] = fmaf(an, w1[j], acc[i][1]);
        }
      }
    }
  }
  float b0 = bl[lane];
  float b1 = bl[64 + lane];
#pragma unroll
  for (int i = 0; i < 4; i++) {
    int r = r0 + i;
    float v0 = acc[i][0] + b0;
    float v1 = acc[i][1] + b1;
    if (WRITE_PRE) {
      out_pre[(size_t)r * 128 + lane] = v0;
      out_pre[(size_t)r * 128 + 64 + lane] = v1;
    }
    out_relu[(size_t)r * 128 + lane] = fmaxf(v0, 0.0f);
    out_relu[(size_t)r * 128 + 64 + lane] = fmaxf(v1, 0.0f);
  }
}

// ---------------- final layer, Cout=64, fused log_softmax over the 64 lanes ----------------
__global__ __launch_bounds__(256)
void sage64_k(const float* __restrict__ x, const float* __restrict__ agg,
              const float* __restrict__ deg,
              const float* __restrict__ Wl, const float* __restrict__ bl,
              const float* __restrict__ Wr,
              float* __restrict__ out) {
  __shared__ __align__(16) float sW[2][128 * 64];   // 2 x 32 KB
  {
    const float4* gl = (const float4*)Wl;
    const float4* gr = (const float4*)Wr;
    float4* sl = (float4*)sW[0];
    float4* sr = (float4*)sW[1];
    for (int i = threadIdx.x; i < 2048; i += 256) { sl[i] = gl[i]; sr[i] = gr[i]; }
  }
  __syncthreads();
  int wave = threadIdx.x >> 6;
  int lane = threadIdx.x & 63;
  int r0 = blockIdx.x * 16 + wave * 4;

  float acc[4] = {0.f, 0.f, 0.f, 0.f};
  float inv[4];
#pragma unroll
  for (int i = 0; i < 4; i++) inv[i] = 1.0f / fmaxf(deg[r0 + i], 1.0f);

  for (int kb = 0; kb < 16; kb++) {
    int k0 = kb * 8;
    float wl[8], wr[8];
#pragma unroll
    for (int j = 0; j < 8; j++) {
      wl[j] = sW[0][(k0 + j) * 64 + lane];
      wr[j] = sW[1][(k0 + j) * 64 + lane];
    }
#pragma unroll
    for (int i = 0; i < 4; i++) {
      int r = r0 + i;
      float4 x0 = *(const float4*)(x + (size_t)r * 128 + k0);
      float4 x1 = *(const float4*)(x + (size_t)r * 128 + k0 + 4);
      float4 a0 = *(const float4*)(agg + (size_t)r * 128 + k0);
      float4 a1 = *(const float4*)(agg + (size_t)r * 128 + k0 + 4);
      float xf[8] = {x0.x, x0.y, x0.z, x0.w, x1.x, x1.y, x1.z, x1.w};
      float af[8] = {a0.x, a0.y, a0.z, a0.w, a1.x, a1.y, a1.z, a1.w};
#pragma unroll
      for (int j = 0; j < 8; j++) {
        acc[i] = fmaf(af[j] * inv[i], wl[j], acc[i]);
        acc[i] = fmaf(xf[j], wr[j], acc[i]);
      }
    }
  }
  float b = bl[lane];
#pragma unroll
  for (int i = 0; i < 4; i++) {
    float v = acc[i] + b;
    float m = v;
#pragma unroll
    for (int off = 32; off > 0; off >>= 1) m = fmaxf(m, __shfl_xor(m, off));
    float e = __expf(v - m);
    float s = e;
#pragma unroll
    for (int off = 32; off > 0; off >>= 1) s += __shfl_xor(s, off);
    float ls = v - m - __logf(s);
    out[(size_t)(r0 + i) * 64 + lane] = ls;
  }
}

// ---------------- graph pooling ----------------
__global__ __launch_bounds__(256)
void pool_scatter_k(const float* __restrict__ x2, const int* __restrict__ cluster,
                    float* __restrict__ gsum, float* __restrict__ gcnt) {
  int tid = blockIdx.x * 256 + threadIdx.x;
  int n = tid >> 5;
  if (n >= NN) return;
  int q = tid & 31;
  int c = cluster[n];
  float4 p = *(const float4*)(x2 + (size_t)n * 128 + q * 4);
  float* gr = gsum + (size_t)c * 128 + q * 4;
  atomicAdd(gr + 0, p.x);
  atomicAdd(gr + 1, p.y);
  atomicAdd(gr + 2, p.z);
  atomicAdd(gr + 3, p.w);
  if (q == 0) atomicAdd(gcnt + c, 1.0f);
}

__global__ __launch_bounds__(256)
void pool_norm_k(const float* __restrict__ gsum, const float* __restrict__ gcnt,
                 float* __restrict__ g) {
  int tid = blockIdx.x * 256 + threadIdx.x;
  if (tid >= NG * 128) return;
  float cnt = fmaxf(gcnt[tid >> 7], 1.0f);
  g[tid] = gsum[tid] / cnt;
}

extern "C" void kernel_launch(void* const* d_in, const int* in_sizes, int n_in,
                              void* d_out, int out_size, void* d_ws, size_t ws_size,
                              hipStream_t stream) {
  const float* x   = (const float*)d_in[0];
  const int*   ei  = (const int*)d_in[1];
  const int*   cl  = (const int*)d_in[2];
  const float* Wl0 = (const float*)d_in[3];
  const float* bl0 = (const float*)d_in[4];
  const float* Wr0 = (const float*)d_in[5];
  const float* Wl1 = (const float*)d_in[6];
  const float* bl1 = (const float*)d_in[7];
  const float* Wr1 = (const float*)d_in[8];
  const float* Wl2 = (const float*)d_in[9];
  const float* bl2 = (const float*)d_in[10];
  const float* Wr2 = (const float*)d_in[11];
  float* out = (float*)d_out;

  char* ws = (char*)d_ws;
  float* agg  = (float*)(ws);                  // 25,600,000 B
  float* deg  = (float*)(ws + 25600000);       //    200,000 B
  float* x1   = (float*)(ws + 25800704);       // 25,600,000 B
  float* x2   = (float*)(ws + 51400704);       // 25,600,000 B
  float* gsum = (float*)(ws + 77000704);       //    262,144 B
  float* gcnt = (float*)(ws + 77262848);       //      2,048 B
  // total ws use: ~77.3 MB

  float* out_lsm = out;            // [50000,64]
  float* out_pre = out + 3200000;  // [50000,128]
  float* out_g   = out + 9600000;  // [512,128]

  // layer 0
  hipMemsetAsync(ws, 0, 25800192, stream);                      // agg + deg
  scatter_k<true><<<75000, 256, 0, stream>>>(x, ei, agg, deg);
  sage128_k<false><<<3125, 256, 0, stream>>>(x, agg, deg, Wl0, bl0, Wr0, x1, nullptr);

  // layer 1 (pre-relu straight to d_out, relu to x2)
  hipMemsetAsync(agg, 0, 25600000, stream);
  scatter_k<false><<<75000, 256, 0, stream>>>(x1, ei, agg, deg);
  sage128_k<true><<<3125, 256, 0, stream>>>(x1, agg, deg, Wl1, bl1, Wr1, x2, out_pre);

  // graph pooling of x2
  hipMemsetAsync(gsum, 0, 264192, stream);
  pool_scatter_k<<<6250, 256, 0, stream>>>(x2, cl, gsum, gcnt);
  pool_norm_k<<<256, 256, 0, stream>>>(gsum, gcnt, out_g);

  // final layer + log_softmax
  hipMemsetAsync(agg, 0, 25600000, stream);
  scatter_k<false><<<75000, 256, 0, stream>>>(x2, ei, agg, deg);
  sage64_k<<<3125, 256, 0, stream>>>(x2, agg, deg, Wl2, bl2, Wr2, out_lsm);
}

// Round 3
// 1004.437 us; speedup vs baseline: 3.7035x; 3.7035x over previous
//
#include <hip/hip_runtime.h>
#include <math.h>

#define NN 50000
#define NE 600000
#define NG 512

// ================= CSR build (once per launch; edge_index constant across layers) ========
__global__ __launch_bounds__(256)
void deg_count_k(const int* __restrict__ ei, int* __restrict__ deg) {
  int e = blockIdx.x * 256 + threadIdx.x;
  if (e >= NE) return;
  atomicAdd(&deg[ei[NE + e]], 1);
}

// single-block exclusive scan over deg[50000] -> row_ptr[50001] and cursor copy
__global__ __launch_bounds__(1024)
void scan_k(const int* __restrict__ deg, int* __restrict__ row_ptr, int* __restrict__ cursor) {
  __shared__ int sums[1024];
  const int CH = 49;                 // 1024*49 = 50176 >= 50000
  int t = threadIdx.x;
  int base = t * CH;
  int s = 0;
  for (int i = 0; i < CH; i++) { int idx = base + i; if (idx < NN) s += deg[idx]; }
  sums[t] = s;
  __syncthreads();
  for (int off = 1; off < 1024; off <<= 1) {
    int v = (t >= off) ? sums[t - off] : 0;
    __syncthreads();
    sums[t] += v;
    __syncthreads();
  }
  int prefix = (t == 0) ? 0 : sums[t - 1];
  for (int i = 0; i < CH; i++) {
    int idx = base + i;
    if (idx < NN) { row_ptr[idx] = prefix; cursor[idx] = prefix; prefix += deg[idx]; }
  }
  if (t == 1023) row_ptr[NN] = sums[1023];
}

__global__ __launch_bounds__(256)
void fill_k(const int* __restrict__ ei, int* __restrict__ cursor, int* __restrict__ perm) {
  int e = blockIdx.x * 256 + threadIdx.x;
  if (e >= NE) return;
  int pos = atomicAdd(&cursor[ei[NE + e]], 1);
  perm[pos] = ei[e];
}

// ============ gather-mean: agg[n] = (sum_{e in in(n)} x[perm[e]]) / max(deg,1) ============
// one wave per node; lane owns channels (2*lane, 2*lane+1)
__global__ __launch_bounds__(256)
void gather_k(const float* __restrict__ x, const int* __restrict__ row_ptr,
              const int* __restrict__ perm, float* __restrict__ agg) {
  int wave = threadIdx.x >> 6;
  int lane = threadIdx.x & 63;
  int n = blockIdx.x * 4 + wave;          // 12500 * 4 = 50000 exactly
  int beg = row_ptr[n], end = row_ptr[n + 1];
  float ax = 0.f, ay = 0.f;
  for (int e = beg; e < end; e++) {
    int src = perm[e];
    float2 v = *(const float2*)(x + (size_t)src * 128 + lane * 2);
    ax += v.x; ay += v.y;
  }
  float inv = 1.0f / fmaxf((float)(end - beg), 1.0f);
  float2 o = {ax * inv, ay * inv};
  *(float2*)(agg + (size_t)n * 128 + lane * 2) = o;
}

// ---------------- fused SAGE layer, Cout=128: out = aggn@Wl + bl + x@Wr ----------------
// agg is pre-normalized by gather_k. Two passes (Wl then Wr) over 64KB LDS.
template<bool WRITE_PRE>
__global__ __launch_bounds__(256)
void sage128_k(const float* __restrict__ x, const float* __restrict__ agg,
               const float* __restrict__ Wl, const float* __restrict__ bl,
               const float* __restrict__ Wr,
               float* __restrict__ out_relu, float* __restrict__ out_pre) {
  __shared__ __align__(16) float sW[128 * 128];   // 64 KB, reused across two passes
  int wave = threadIdx.x >> 6;
  int lane = threadIdx.x & 63;
  int r0 = blockIdx.x * 16 + wave * 4;   // 3125 * 16 = 50000

  float acc[4][2];
#pragma unroll
  for (int i = 0; i < 4; i++) { acc[i][0] = 0.0f; acc[i][1] = 0.0f; }

  for (int pass = 0; pass < 2; pass++) {
    const float* Wg = pass ? Wr : Wl;
    const float* src = pass ? x : agg;
    __syncthreads();
    {
      const float4* g = (const float4*)Wg;
      float4* s = (float4*)sW;
      for (int i = threadIdx.x; i < 4096; i += 256) s[i] = g[i];
    }
    __syncthreads();

    for (int kb = 0; kb < 16; kb++) {
      int k0 = kb * 8;
      float w0[8], w1[8];
#pragma unroll
      for (int j = 0; j < 8; j++) {
        w0[j] = sW[(k0 + j) * 128 + lane];
        w1[j] = sW[(k0 + j) * 128 + 64 + lane];
      }
#pragma unroll
      for (int i = 0; i < 4; i++) {
        int r = r0 + i;
        float4 a0 = *(const float4*)(src + (size_t)r * 128 + k0);
        float4 a1 = *(const float4*)(src + (size_t)r * 128 + k0 + 4);
        float vin[8] = {a0.x, a0.y, a0.z, a0.w, a1.x, a1.y, a1.z, a1.w};
#pragma unroll
        for (int j = 0; j < 8; j++) {
          acc[i][0] = fmaf(vin[j], w0[j], acc[i][0]);
          acc[i][1] = fmaf(vin[j], w1[j], acc[i][1]);
        }
      }
    }
  }
  float b0 = bl[lane];
  float b1 = bl[64 + lane];
#pragma unroll
  for (int i = 0; i < 4; i++) {
    int r = r0 + i;
    float v0 = acc[i][0] + b0;
    float v1 = acc[i][1] + b1;
    if (WRITE_PRE) {
      out_pre[(size_t)r * 128 + lane] = v0;
      out_pre[(size_t)r * 128 + 64 + lane] = v1;
    }
    out_relu[(size_t)r * 128 + lane] = fmaxf(v0, 0.0f);
    out_relu[(size_t)r * 128 + 64 + lane] = fmaxf(v1, 0.0f);
  }
}

// ---------------- final layer, Cout=64, fused log_softmax over the 64 lanes ----------------
__global__ __launch_bounds__(256)
void sage64_k(const float* __restrict__ x, const float* __restrict__ agg,
              const float* __restrict__ Wl, const float* __restrict__ bl,
              const float* __restrict__ Wr,
              float* __restrict__ out) {
  __shared__ __align__(16) float sW[2][128 * 64];   // 2 x 32 KB
  {
    const float4* gl = (const float4*)Wl;
    const float4* gr = (const float4*)Wr;
    float4* sl = (float4*)sW[0];
    float4* sr = (float4*)sW[1];
    for (int i = threadIdx.x; i < 2048; i += 256) { sl[i] = gl[i]; sr[i] = gr[i]; }
  }
  __syncthreads();
  int wave = threadIdx.x >> 6;
  int lane = threadIdx.x & 63;
  int r0 = blockIdx.x * 16 + wave * 4;

  float acc[4] = {0.f, 0.f, 0.f, 0.f};

  for (int kb = 0; kb < 16; kb++) {
    int k0 = kb * 8;
    float wl[8], wr[8];
#pragma unroll
    for (int j = 0; j < 8; j++) {
      wl[j] = sW[0][(k0 + j) * 64 + lane];
      wr[j] = sW[1][(k0 + j) * 64 + lane];
    }
#pragma unroll
    for (int i = 0; i < 4; i++) {
      int r = r0 + i;
      float4 x0 = *(const float4*)(x + (size_t)r * 128 + k0);
      float4 x1 = *(const float4*)(x + (size_t)r * 128 + k0 + 4);
      float4 a0 = *(const float4*)(agg + (size_t)r * 128 + k0);
      float4 a1 = *(const float4*)(agg + (size_t)r * 128 + k0 + 4);
      float xf[8] = {x0.x, x0.y, x0.z, x0.w, x1.x, x1.y, x1.z, x1.w};
      float af[8] = {a0.x, a0.y, a0.z, a0.w, a1.x, a1.y, a1.z, a1.w};
#pragma unroll
      for (int j = 0; j < 8; j++) {
        acc[i] = fmaf(af[j], wl[j], acc[i]);
        acc[i] = fmaf(xf[j], wr[j], acc[i]);
      }
    }
  }
  float b = bl[lane];
#pragma unroll
  for (int i = 0; i < 4; i++) {
    float v = acc[i] + b;
    float m = v;
#pragma unroll
    for (int off = 32; off > 0; off >>= 1) m = fmaxf(m, __shfl_xor(m, off));
    float e = __expf(v - m);
    float s = e;
#pragma unroll
    for (int off = 32; off > 0; off >>= 1) s += __shfl_xor(s, off);
    float ls = v - m - __logf(s);
    out[(size_t)(r0 + i) * 64 + lane] = ls;
  }
}

// ---------------- graph pooling ----------------
__global__ __launch_bounds__(256)
void pool_scatter_k(const float* __restrict__ x2, const int* __restrict__ cluster,
                    float* __restrict__ gsum, float* __restrict__ gcnt) {
  int tid = blockIdx.x * 256 + threadIdx.x;
  int n = tid >> 5;
  if (n >= NN) return;
  int q = tid & 31;
  int c = cluster[n];
  float4 p = *(const float4*)(x2 + (size_t)n * 128 + q * 4);
  float* gr = gsum + (size_t)c * 128 + q * 4;
  atomicAdd(gr + 0, p.x);
  atomicAdd(gr + 1, p.y);
  atomicAdd(gr + 2, p.z);
  atomicAdd(gr + 3, p.w);
  if (q == 0) atomicAdd(gcnt + c, 1.0f);
}

__global__ __launch_bounds__(256)
void pool_norm_k(const float* __restrict__ gsum, const float* __restrict__ gcnt,
                 float* __restrict__ g) {
  int tid = blockIdx.x * 256 + threadIdx.x;
  if (tid >= NG * 128) return;
  float cnt = fmaxf(gcnt[tid >> 7], 1.0f);
  g[tid] = gsum[tid] / cnt;
}

extern "C" void kernel_launch(void* const* d_in, const int* in_sizes, int n_in,
                              void* d_out, int out_size, void* d_ws, size_t ws_size,
                              hipStream_t stream) {
  const float* x   = (const float*)d_in[0];
  const int*   ei  = (const int*)d_in[1];
  const int*   cl  = (const int*)d_in[2];
  const float* Wl0 = (const float*)d_in[3];
  const float* bl0 = (const float*)d_in[4];
  const float* Wr0 = (const float*)d_in[5];
  const float* Wl1 = (const float*)d_in[6];
  const float* bl1 = (const float*)d_in[7];
  const float* Wr1 = (const float*)d_in[8];
  const float* Wl2 = (const float*)d_in[9];
  const float* bl2 = (const float*)d_in[10];
  const float* Wr2 = (const float*)d_in[11];
  float* out = (float*)d_out;

  char* ws = (char*)d_ws;
  float* agg     = (float*)(ws);                  // 25,600,000 B
  float* x1      = (float*)(ws + 25600000);       // 25,600,000 B
  float* x2      = (float*)(ws + 51200000);       // 25,600,000 B
  int*   deg     = (int*)  (ws + 76800000);       //    200,000 B
  int*   row_ptr = (int*)  (ws + 77000192);       //    200,004 B (+pad)
  int*   cursor  = (int*)  (ws + 77200896);       //    200,000 B
  int*   perm    = (int*)  (ws + 77400896);       //  2,400,000 B
  float* gsum    = (float*)(ws + 79801344);       //    262,144 B
  float* gcnt    = (float*)(ws + 80063488);       //      2,048 B
  // total ~80.1 MB

  float* out_lsm = out;            // [50000,64]
  float* out_pre = out + 3200000;  // [50000,128]
  float* out_g   = out + 9600000;  // [512,128]

  // ---- CSR build (once) ----
  hipMemsetAsync(deg, 0, 200000, stream);
  deg_count_k<<<2344, 256, 0, stream>>>(ei, deg);
  scan_k<<<1, 1024, 0, stream>>>(deg, row_ptr, cursor);
  fill_k<<<2344, 256, 0, stream>>>(ei, cursor, perm);

  // ---- layer 0 ----
  gather_k<<<12500, 256, 0, stream>>>(x, row_ptr, perm, agg);
  sage128_k<false><<<3125, 256, 0, stream>>>(x, agg, Wl0, bl0, Wr0, x1, nullptr);

  // ---- layer 1 (pre-relu straight to d_out, relu to x2) ----
  gather_k<<<12500, 256, 0, stream>>>(x1, row_ptr, perm, agg);
  sage128_k<true><<<3125, 256, 0, stream>>>(x1, agg, Wl1, bl1, Wr1, x2, out_pre);

  // ---- graph pooling of x2 ----
  hipMemsetAsync(gsum, 0, 264192, stream);
  pool_scatter_k<<<6250, 256, 0, stream>>>(x2, cl, gsum, gcnt);
  pool_norm_k<<<256, 256, 0, stream>>>(gsum, gcnt, out_g);

  // ---- final layer + log_softmax ----
  gather_k<<<12500, 256, 0, stream>>>(x2, row_ptr, perm, agg);
  sage64_k<<<3125, 256, 0, stream>>>(x2, agg, Wl2, bl2, Wr2, out_lsm);
}

// Round 4
// 815.580 us; speedup vs baseline: 4.5611x; 1.2316x over previous
//
#include <hip/hip_runtime.h>
#include <math.h>

#define NN 50000
#define NE 600000
#define NG 512

// ================= CSR build (once per launch; edge_index constant across layers) ========
__global__ __launch_bounds__(256)
void deg_count_k(const int* __restrict__ ei, int* __restrict__ deg) {
  int e = blockIdx.x * 256 + threadIdx.x;
  if (e >= NE) return;
  atomicAdd(&deg[ei[NE + e]], 1);
}

// single-block exclusive scan over deg[50000] -> row_ptr[50001] and cursor copy
__global__ __launch_bounds__(1024)
void scan_k(const int* __restrict__ deg, int* __restrict__ row_ptr, int* __restrict__ cursor) {
  __shared__ int sums[1024];
  const int CH = 49;                 // 1024*49 = 50176 >= 50000
  int t = threadIdx.x;
  int base = t * CH;
  int s = 0;
  for (int i = 0; i < CH; i++) { int idx = base + i; if (idx < NN) s += deg[idx]; }
  sums[t] = s;
  __syncthreads();
  for (int off = 1; off < 1024; off <<= 1) {
    int v = (t >= off) ? sums[t - off] : 0;
    __syncthreads();
    sums[t] += v;
    __syncthreads();
  }
  int prefix = (t == 0) ? 0 : sums[t - 1];
  for (int i = 0; i < CH; i++) {
    int idx = base + i;
    if (idx < NN) { row_ptr[idx] = prefix; cursor[idx] = prefix; prefix += deg[idx]; }
  }
  if (t == 1023) row_ptr[NN] = sums[1023];
}

__global__ __launch_bounds__(256)
void fill_k(const int* __restrict__ ei, int* __restrict__ cursor, int* __restrict__ perm) {
  int e = blockIdx.x * 256 + threadIdx.x;
  if (e >= NE) return;
  int pos = atomicAdd(&cursor[ei[NE + e]], 1);
  perm[pos] = ei[e];
}

// ============ gather-mean: agg[n] = (sum_{e in in(n)} x[perm[e]]) / max(deg,1) ============
// one wave per node; lane owns channels (2*lane, 2*lane+1); 4-edge unroll for MLP.
__global__ __launch_bounds__(256)
void gather_k(const float* __restrict__ x, const int* __restrict__ row_ptr,
              const int* __restrict__ perm, float* __restrict__ agg) {
  int wave = threadIdx.x >> 6;
  int lane = threadIdx.x & 63;
  int n = blockIdx.x * 4 + wave;          // 12500 * 4 = 50000 exactly
  int beg = row_ptr[n], end = row_ptr[n + 1];
  int co = lane * 2;
  float ax0 = 0.f, ay0 = 0.f, ax1 = 0.f, ay1 = 0.f;
  float ax2 = 0.f, ay2 = 0.f, ax3 = 0.f, ay3 = 0.f;
  int e = beg;
  for (; e + 4 <= end; e += 4) {
    int s0 = perm[e + 0], s1 = perm[e + 1], s2 = perm[e + 2], s3 = perm[e + 3];
    float2 v0 = *(const float2*)(x + (size_t)s0 * 128 + co);
    float2 v1 = *(const float2*)(x + (size_t)s1 * 128 + co);
    float2 v2 = *(const float2*)(x + (size_t)s2 * 128 + co);
    float2 v3 = *(const float2*)(x + (size_t)s3 * 128 + co);
    ax0 += v0.x; ay0 += v0.y; ax1 += v1.x; ay1 += v1.y;
    ax2 += v2.x; ay2 += v2.y; ax3 += v3.x; ay3 += v3.y;
  }
  for (; e < end; e++) {
    int s0 = perm[e];
    float2 v = *(const float2*)(x + (size_t)s0 * 128 + co);
    ax0 += v.x; ay0 += v.y;
  }
  float inv = 1.0f / fmaxf((float)(end - beg), 1.0f);
  float2 o = { (ax0 + ax1 + ax2 + ax3) * inv, (ay0 + ay1 + ay2 + ay3) * inv };
  *(float2*)(agg + (size_t)n * 128 + co) = o;
}

// ---------------- fused SAGE layer, Cout=128: out = aggn@Wl + bl + x@Wr ----------------
// agg is pre-normalized by gather_k. Two passes (Wl then Wr) over 64KB LDS.
template<bool WRITE_PRE>
__global__ __launch_bounds__(256)
void sage128_k(const float* __restrict__ x, const float* __restrict__ agg,
               const float* __restrict__ Wl, const float* __restrict__ bl,
               const float* __restrict__ Wr,
               float* __restrict__ out_relu, float* __restrict__ out_pre) {
  __shared__ __align__(16) float sW[128 * 128];   // 64 KB, reused across two passes
  int wave = threadIdx.x >> 6;
  int lane = threadIdx.x & 63;
  int r0 = blockIdx.x * 16 + wave * 4;   // 3125 * 16 = 50000

  float acc[4][2];
#pragma unroll
  for (int i = 0; i < 4; i++) { acc[i][0] = 0.0f; acc[i][1] = 0.0f; }

  for (int pass = 0; pass < 2; pass++) {
    const float* Wg = pass ? Wr : Wl;
    const float* src = pass ? x : agg;
    __syncthreads();
    {
      const float4* g = (const float4*)Wg;
      float4* s = (float4*)sW;
      for (int i = threadIdx.x; i < 4096; i += 256) s[i] = g[i];
    }
    __syncthreads();

    for (int kb = 0; kb < 16; kb++) {
      int k0 = kb * 8;
      float w0[8], w1[8];
#pragma unroll
      for (int j = 0; j < 8; j++) {
        w0[j] = sW[(k0 + j) * 128 + lane];
        w1[j] = sW[(k0 + j) * 128 + 64 + lane];
      }
#pragma unroll
      for (int i = 0; i < 4; i++) {
        int r = r0 + i;
        float4 a0 = *(const float4*)(src + (size_t)r * 128 + k0);
        float4 a1 = *(const float4*)(src + (size_t)r * 128 + k0 + 4);
        float vin[8] = {a0.x, a0.y, a0.z, a0.w, a1.x, a1.y, a1.z, a1.w};
#pragma unroll
        for (int j = 0; j < 8; j++) {
          acc[i][0] = fmaf(vin[j], w0[j], acc[i][0]);
          acc[i][1] = fmaf(vin[j], w1[j], acc[i][1]);
        }
      }
    }
  }
  float b0 = bl[lane];
  float b1 = bl[64 + lane];
#pragma unroll
  for (int i = 0; i < 4; i++) {
    int r = r0 + i;
    float v0 = acc[i][0] + b0;
    float v1 = acc[i][1] + b1;
    if (WRITE_PRE) {
      out_pre[(size_t)r * 128 + lane] = v0;
      out_pre[(size_t)r * 128 + 64 + lane] = v1;
    }
    out_relu[(size_t)r * 128 + lane] = fmaxf(v0, 0.0f);
    out_relu[(size_t)r * 128 + 64 + lane] = fmaxf(v1, 0.0f);
  }
}

// ---------------- final layer, Cout=64, fused log_softmax over the 64 lanes ----------------
__global__ __launch_bounds__(256)
void sage64_k(const float* __restrict__ x, const float* __restrict__ agg,
              const float* __restrict__ Wl, const float* __restrict__ bl,
              const float* __restrict__ Wr,
              float* __restrict__ out) {
  __shared__ __align__(16) float sW[2][128 * 64];   // 2 x 32 KB
  {
    const float4* gl = (const float4*)Wl;
    const float4* gr = (const float4*)Wr;
    float4* sl = (float4*)sW[0];
    float4* sr = (float4*)sW[1];
    for (int i = threadIdx.x; i < 2048; i += 256) { sl[i] = gl[i]; sr[i] = gr[i]; }
  }
  __syncthreads();
  int wave = threadIdx.x >> 6;
  int lane = threadIdx.x & 63;
  int r0 = blockIdx.x * 16 + wave * 4;

  float acc[4] = {0.f, 0.f, 0.f, 0.f};

  for (int kb = 0; kb < 16; kb++) {
    int k0 = kb * 8;
    float wl[8], wr[8];
#pragma unroll
    for (int j = 0; j < 8; j++) {
      wl[j] = sW[0][(k0 + j) * 64 + lane];
      wr[j] = sW[1][(k0 + j) * 64 + lane];
    }
#pragma unroll
    for (int i = 0; i < 4; i++) {
      int r = r0 + i;
      float4 x0 = *(const float4*)(x + (size_t)r * 128 + k0);
      float4 x1 = *(const float4*)(x + (size_t)r * 128 + k0 + 4);
      float4 a0 = *(const float4*)(agg + (size_t)r * 128 + k0);
      float4 a1 = *(const float4*)(agg + (size_t)r * 128 + k0 + 4);
      float xf[8] = {x0.x, x0.y, x0.z, x0.w, x1.x, x1.y, x1.z, x1.w};
      float af[8] = {a0.x, a0.y, a0.z, a0.w, a1.x, a1.y, a1.z, a1.w};
#pragma unroll
      for (int j = 0; j < 8; j++) {
        acc[i] = fmaf(af[j], wl[j], acc[i]);
        acc[i] = fmaf(xf[j], wr[j], acc[i]);
      }
    }
  }
  float b = bl[lane];
#pragma unroll
  for (int i = 0; i < 4; i++) {
    float v = acc[i] + b;
    float m = v;
#pragma unroll
    for (int off = 32; off > 0; off >>= 1) m = fmaxf(m, __shfl_xor(m, off));
    float e = __expf(v - m);
    float s = e;
#pragma unroll
    for (int off = 32; off > 0; off >>= 1) s += __shfl_xor(s, off);
    float ls = v - m - __logf(s);
    out[(size_t)(r0 + i) * 64 + lane] = ls;
  }
}

// ---------------- graph pooling: cluster is SORTED -> segmented mean, no atomics ----------
// one block (128 threads) per graph; binary-search the segment, then channel-coalesced sum.
__global__ __launch_bounds__(128)
void pool_seg_k(const float* __restrict__ x2, const int* __restrict__ cluster,
                float* __restrict__ g) {
  int gid = blockIdx.x;          // 512
  int ch = threadIdx.x;          // 128
  int lo = 0, hi = NN;
  while (lo < hi) { int mid = (lo + hi) >> 1; if (cluster[mid] < gid) lo = mid + 1; else hi = mid; }
  int beg = lo;
  hi = NN;
  while (lo < hi) { int mid = (lo + hi) >> 1; if (cluster[mid] < gid + 1) lo = mid + 1; else hi = mid; }
  int end = lo;
  float s = 0.f;
  for (int n = beg; n < end; n++) s += x2[(size_t)n * 128 + ch];
  g[gid * 128 + ch] = s / fmaxf((float)(end - beg), 1.0f);
}

extern "C" void kernel_launch(void* const* d_in, const int* in_sizes, int n_in,
                              void* d_out, int out_size, void* d_ws, size_t ws_size,
                              hipStream_t stream) {
  const float* x   = (const float*)d_in[0];
  const int*   ei  = (const int*)d_in[1];
  const int*   cl  = (const int*)d_in[2];
  const float* Wl0 = (const float*)d_in[3];
  const float* bl0 = (const float*)d_in[4];
  const float* Wr0 = (const float*)d_in[5];
  const float* Wl1 = (const float*)d_in[6];
  const float* bl1 = (const float*)d_in[7];
  const float* Wr1 = (const float*)d_in[8];
  const float* Wl2 = (const float*)d_in[9];
  const float* bl2 = (const float*)d_in[10];
  const float* Wr2 = (const float*)d_in[11];
  float* out = (float*)d_out;

  char* ws = (char*)d_ws;
  float* agg     = (float*)(ws);                  // 25,600,000 B
  float* x1      = (float*)(ws + 25600000);       // 25,600,000 B
  float* x2      = (float*)(ws + 51200000);       // 25,600,000 B
  int*   deg     = (int*)  (ws + 76800000);       //    200,000 B
  int*   row_ptr = (int*)  (ws + 77000192);       //    200,004 B (+pad)
  int*   cursor  = (int*)  (ws + 77200896);       //    200,000 B
  int*   perm    = (int*)  (ws + 77400896);       //  2,400,000 B

  float* out_lsm = out;            // [50000,64]
  float* out_pre = out + 3200000;  // [50000,128]
  float* out_g   = out + 9600000;  // [512,128]

  // ---- CSR build (once) ----
  hipMemsetAsync(deg, 0, 200000, stream);
  deg_count_k<<<2344, 256, 0, stream>>>(ei, deg);
  scan_k<<<1, 1024, 0, stream>>>(deg, row_ptr, cursor);
  fill_k<<<2344, 256, 0, stream>>>(ei, cursor, perm);

  // ---- layer 0 ----
  gather_k<<<12500, 256, 0, stream>>>(x, row_ptr, perm, agg);
  sage128_k<false><<<3125, 256, 0, stream>>>(x, agg, Wl0, bl0, Wr0, x1, nullptr);

  // ---- layer 1 (pre-relu straight to d_out, relu to x2) ----
  gather_k<<<12500, 256, 0, stream>>>(x1, row_ptr, perm, agg);
  sage128_k<true><<<3125, 256, 0, stream>>>(x1, agg, Wl1, bl1, Wr1, x2, out_pre);

  // ---- graph pooling of x2 (sorted clusters -> segmented, no atomics) ----
  pool_seg_k<<<NG, 128, 0, stream>>>(x2, cl, out_g);

  // ---- final layer + log_softmax ----
  gather_k<<<12500, 256, 0, stream>>>(x2, row_ptr, perm, agg);
  sage64_k<<<3125, 256, 0, stream>>>(x2, agg, Wl2, bl2, Wr2, out_lsm);
}